// Round 1
// 5055.020 us; speedup vs baseline: 1.7118x; 1.7118x over previous
//
#include <hip/hip_runtime.h>
#include <stdint.h>

#define N_ROWS 32768
#define DIM    512
#define NQ     4
#define NCODES 2048
#define BETA   0.25
#define EPS_RESCUE 0.02f   // MFMA-score gap below which we np-mimic rescore ALL codes

typedef __attribute__((ext_vector_type(8))) short bf16x8;
typedef __attribute__((ext_vector_type(4))) float f32x4;

// ---- ws layout (bytes) ----
#define WS_LOSS   0          // 512 doubles (4 KB)
#define WS_CN     4096       // Q*K floats (32 KB)
#define WS_GAP    36864      // N floats (128 KB)
#define WS_PART   167936     // 16 * N float4 (8 MB)
#define WS_CBH    8556544    // Q*K*D ushort (8 MB)
#define WS_CBL    16945152   // Q*K*D ushort (8 MB)

__device__ __forceinline__ ushort f2bf(float f) {
  union { float f; uint32_t u; } v; v.f = f;
  uint32_t r = v.u + 0x7fffu + ((v.u >> 16) & 1u);
  return (ushort)(r >> 16);
}
__device__ __forceinline__ float bf2f(ushort h) {
  union { uint32_t u; float f; } v; v.u = ((uint32_t)h) << 16; return v.f;
}

// ---- numpy pairwise sum (blocksize 128, 8-way unrolled) of squares of 512 floats ----
__device__ __forceinline__ float np_pairwise_sq512(const float* buf, int lane) {
  const int blk = lane >> 3, j = lane & 7;
  const float* p = buf + ((lane < 32) ? (blk * 128 + j) : 0);
  float a = p[0];
  float acc = __fmul_rn(a, a);
#pragma unroll
  for (int i = 1; i < 16; ++i) {
    a = p[i * 8];
    acc = __fadd_rn(acc, __fmul_rn(a, a));
  }
  float s[4];
#pragma unroll
  for (int b = 0; b < 4; ++b) {
    const float p0 = __shfl(acc, b * 8 + 0), p1 = __shfl(acc, b * 8 + 1);
    const float p2 = __shfl(acc, b * 8 + 2), p3 = __shfl(acc, b * 8 + 3);
    const float p4 = __shfl(acc, b * 8 + 4), p5 = __shfl(acc, b * 8 + 5);
    const float p6 = __shfl(acc, b * 8 + 6), p7 = __shfl(acc, b * 8 + 7);
    s[b] = __fadd_rn(__fadd_rn(__fadd_rn(p0, p1), __fadd_rn(p2, p3)),
                     __fadd_rn(__fadd_rn(p4, p5), __fadd_rn(p6, p7)));
  }
  return __fadd_rn(__fadd_rn(s[0], s[1]), __fadd_rn(s[2], s[3]));
}

__global__ __launch_bounds__(64)
void cnorm_kernel(const float* __restrict__ cb, float* __restrict__ Cn) {
  const int row = blockIdx.x, lane = threadIdx.x;
  __shared__ float buf[DIM];
  const float* p = cb + (size_t)row * DIM + lane * 8;
  float4 a = *(const float4*)p, b = *(const float4*)(p + 4);
  *(float4*)&buf[lane * 8]     = a;
  *(float4*)&buf[lane * 8 + 4] = b;
  __syncthreads();
  const float v = np_pairwise_sq512(buf, lane);
  if (lane == 0) Cn[row] = v;
}

// ---- split codebook into bf16 hi/lo ----
__global__ __launch_bounds__(256)
void cbsplit_kernel(const float* __restrict__ cb, ushort* __restrict__ hi, ushort* __restrict__ lo) {
  const size_t i = ((size_t)blockIdx.x * 256 + threadIdx.x) * 8;
  float4 a = *(const float4*)(cb + i), b = *(const float4*)(cb + i + 4);
  const float f[8] = {a.x, a.y, a.z, a.w, b.x, b.y, b.z, b.w};
  ushort h[8], l[8];
#pragma unroll
  for (int j = 0; j < 8; ++j) {
    h[j] = f2bf(f[j]);
    l[j] = f2bf(f[j] - bf2f(h[j]));
  }
  *(ushort4*)(hi + i)     = make_ushort4(h[0], h[1], h[2], h[3]);
  *(ushort4*)(hi + i + 4) = make_ushort4(h[4], h[5], h[6], h[7]);
  *(ushort4*)(lo + i)     = make_ushort4(l[0], l[1], l[2], l[3]);
  *(ushort4*)(lo + i + 4) = make_ushort4(l[4], l[5], l[6], l[7]);
}

__device__ __forceinline__ void top2_insert(float s, int c, float& v1, int& i1, float& v2, int& i2) {
  if (s > v1 || (s == v1 && c < i1)) { v2 = v1; i2 = i1; v1 = s; i1 = c; }
  else if (s > v2 || (s == v2 && c < i2)) { v2 = s; i2 = c; }
}

// ---------------- MFMA bf16x3 score + per-(rowtile,codetile) top-2 ----------------
// Block 256 (4 waves): tile 64 rows x 128 codes, K looped in chunks of 32.
// Wave w owns codes [w*32, w*32+32): n-tiles nt=0,1; m-tiles mt=0..3.
__global__ __launch_bounds__(256, 2)
void argmax_kernel(const float* __restrict__ x, const float* __restrict__ xq_acc,
                   const ushort* __restrict__ cbh, const ushort* __restrict__ cbl,
                   const float* __restrict__ Cn, float4* __restrict__ partials, int stage)
{
  __shared__ ushort Ah[64 * 32], Al[64 * 32], Bh[128 * 32], Bl[128 * 32];
  __shared__ float4 mbuf[4][64];

  const int t    = threadIdx.x;
  const int lane = t & 63, w = t >> 6;
  const int rt = blockIdx.x & 511, ct = blockIdx.x >> 9;
  const int m0 = rt * 64, c0 = ct * 128;
  const int arow = t >> 2, aseg = (t & 3) * 8;
  const int lm = lane & 15, lq = lane >> 4;

  f32x4 acc[4][2];
#pragma unroll
  for (int mt = 0; mt < 4; ++mt)
#pragma unroll
    for (int nt = 0; nt < 2; ++nt) acc[mt][nt] = (f32x4){0.f, 0.f, 0.f, 0.f};

  for (int kc = 0; kc < 16; ++kc) {
    const int k0 = kc * 32;
    __syncthreads();
    // ---- B: async global->LDS, 16B per lane (LDS addr = uniform + lane*16) ----
#pragma unroll
    for (int i = 0; i < 2; ++i) {
      const int s = i * 256 + t;                       // 0..511: code=s>>2, kseg=s&3
      const size_t g = (size_t)(c0 + (s >> 2)) * DIM + k0 + (s & 3) * 8;
      __builtin_amdgcn_global_load_lds((__attribute__((address_space(1))) void*)(cbh + g),
                                       (__attribute__((address_space(3))) void*)&Bh[s * 8], 16, 0, 0);
      __builtin_amdgcn_global_load_lds((__attribute__((address_space(1))) void*)(cbl + g),
                                       (__attribute__((address_space(3))) void*)&Bl[s * 8], 16, 0, 0);
    }
    // ---- A: load fp32 residual chunk, split hi/lo, store LDS ----
    {
      const size_t g = (size_t)(m0 + arow) * DIM + k0 + aseg;
      float4 v0 = *(const float4*)(x + g), v1 = *(const float4*)(x + g + 4);
      if (stage) {
        float4 q0 = *(const float4*)(xq_acc + g), q1 = *(const float4*)(xq_acc + g + 4);
        v0.x -= q0.x; v0.y -= q0.y; v0.z -= q0.z; v0.w -= q0.w;
        v1.x -= q1.x; v1.y -= q1.y; v1.z -= q1.z; v1.w -= q1.w;
      }
      const float f[8] = {v0.x, v0.y, v0.z, v0.w, v1.x, v1.y, v1.z, v1.w};
      ushort h[8], l[8];
#pragma unroll
      for (int j = 0; j < 8; ++j) {
        h[j] = f2bf(f[j]);
        l[j] = f2bf(f[j] - bf2f(h[j]));
      }
      const int o = arow * 32 + aseg;
      *(ushort4*)&Ah[o]     = make_ushort4(h[0], h[1], h[2], h[3]);
      *(ushort4*)&Ah[o + 4] = make_ushort4(h[4], h[5], h[6], h[7]);
      *(ushort4*)&Al[o]     = make_ushort4(l[0], l[1], l[2], l[3]);
      *(ushort4*)&Al[o + 4] = make_ushort4(l[4], l[5], l[6], l[7]);
    }
    __syncthreads();   // drains vmcnt (global_load_lds) + lgkm (ds_write)
    // ---- fragments: A[m=lm][k=lq*8+j], B[n=lm][k=lq*8+j] (B^T pattern) ----
    bf16x8 ah[4], al[4], bh[2], bl[2];
#pragma unroll
    for (int mt = 0; mt < 4; ++mt) {
      const int o = (mt * 16 + lm) * 32 + lq * 8;
      ah[mt] = *(bf16x8*)&Ah[o];
      al[mt] = *(bf16x8*)&Al[o];
    }
#pragma unroll
    for (int nt = 0; nt < 2; ++nt) {
      const int o = (w * 32 + nt * 16 + lm) * 32 + lq * 8;
      bh[nt] = *(bf16x8*)&Bh[o];
      bl[nt] = *(bf16x8*)&Bl[o];
    }
#pragma unroll
    for (int mt = 0; mt < 4; ++mt)
#pragma unroll
      for (int nt = 0; nt < 2; ++nt) {
        acc[mt][nt] = __builtin_amdgcn_mfma_f32_16x16x32_bf16(ah[mt], bh[nt], acc[mt][nt], 0, 0, 0);
        acc[mt][nt] = __builtin_amdgcn_mfma_f32_16x16x32_bf16(ah[mt], bl[nt], acc[mt][nt], 0, 0, 0);
        acc[mt][nt] = __builtin_amdgcn_mfma_f32_16x16x32_bf16(al[mt], bh[nt], acc[mt][nt], 0, 0, 0);
      }
  }
  // ---- epilogue: score = G - 0.5*||c||^2; top-2 per row across wave's 32 codes ----
  float hc[2]; int cidx[2];
#pragma unroll
  for (int nt = 0; nt < 2; ++nt) {
    cidx[nt] = c0 + w * 32 + nt * 16 + lm;
    hc[nt] = 0.5f * Cn[cidx[nt]];
  }
#pragma unroll
  for (int mt = 0; mt < 4; ++mt)
#pragma unroll
    for (int r = 0; r < 4; ++r) {
      float v1 = -3.4e38f, v2 = -3.4e38f;
      int   i1 = 0x7fffffff, i2 = 0x7fffffff;
#pragma unroll
      for (int nt = 0; nt < 2; ++nt)
        top2_insert(acc[mt][nt][r] - hc[nt], cidx[nt], v1, i1, v2, i2);
#pragma unroll
      for (int off = 1; off < 16; off <<= 1) {   // stays within the 16-lane quad group
        const float ov1 = __shfl_xor(v1, off); const int oi1 = __shfl_xor(i1, off);
        const float ov2 = __shfl_xor(v2, off); const int oi2 = __shfl_xor(i2, off);
        top2_insert(ov1, oi1, v1, i1, v2, i2);
        top2_insert(ov2, oi2, v1, i1, v2, i2);
      }
      if (lm == 0) mbuf[w][mt * 16 + lq * 4 + r] = make_float4(v1, (float)i1, v2, (float)i2);
    }
  __syncthreads();
  if (t < 64) {   // merge the 4 waves' top-2 for row t
    float v1 = -3.4e38f, v2 = -3.4e38f;
    int   i1 = 0x7fffffff, i2 = 0x7fffffff;
#pragma unroll
    for (int ww = 0; ww < 4; ++ww) {
      float4 p = mbuf[ww][t];
      top2_insert(p.x, (int)p.y, v1, i1, v2, i2);
      top2_insert(p.z, (int)p.w, v1, i1, v2, i2);
    }
    partials[(size_t)ct * N_ROWS + m0 + t] = make_float4(v1, (float)i1, v2, (float)i2);
  }
}

// ---- merge 16 code-tile partials per row -> idx + gap ----
__global__ __launch_bounds__(256)
void mergetop_kernel(const float4* __restrict__ partials, float* __restrict__ idx_out,
                     float* __restrict__ gap, int stage)
{
  const int row = blockIdx.x * 256 + threadIdx.x;
  float v1 = -3.4e38f, v2 = -3.4e38f;
  int   i1 = 0x7fffffff, i2 = 0x7fffffff;
#pragma unroll
  for (int ctt = 0; ctt < 16; ++ctt) {
    float4 p = partials[(size_t)ctt * N_ROWS + row];
    top2_insert(p.x, (int)p.y, v1, i1, v2, i2);
    top2_insert(p.z, (int)p.w, v1, i1, v2, i2);
  }
  idx_out[(size_t)row * NQ + stage] = (float)i1;
  gap[row] = v1 - v2;
}

// ---------------- np-fp32-mimic rescue (validated in R4) ----------------
// v2: 4 waves/block, each wave scans a contiguous 512-code chunk; 4-code ILP
// unroll so the dependent fp64 shuffle trees of independent codes pipeline.
// Per-code arithmetic (double dot expression order, xor-reduce off=32..1 order)
// is bit-identical to the validated serial version; segmented argmin merged in
// ascending wave order with the same tie rule reproduces the serial scan.
#define RESCUE_UNROLL 4

__global__ __launch_bounds__(256)
void rescue_kernel(const float* __restrict__ x, const float* __restrict__ cb,
                   const float* __restrict__ Cn, float* __restrict__ idxf,
                   const float* __restrict__ gap, int stage)
{
  const int row = blockIdx.x;
  if (gap[row] >= EPS_RESCUE) return;
  const int t = threadIdx.x;
  const int lane = t & 63, w = t >> 6;
  __shared__ float rs[DIM];
  __shared__ float sd[4];
  __shared__ int   si[4];

  // every wave computes the identical residual f[8] (deterministic replay)
  float f[8];
  {
    const float* xp = x + (size_t)row * DIM + lane * 8;
    float4 a = *(const float4*)xp, b = *(const float4*)(xp + 4);
    f[0]=a.x; f[1]=a.y; f[2]=a.z; f[3]=a.w; f[4]=b.x; f[5]=b.y; f[6]=b.z; f[7]=b.w;
  }
  for (int p = 0; p < stage; ++p) {
    const int ip = (int)idxf[(size_t)row * NQ + p];
    const float* cp = cb + ((size_t)p * NCODES + ip) * DIM + lane * 8;
    float4 a = *(const float4*)cp, b = *(const float4*)(cp + 4);
    const float q[8] = {a.x, a.y, a.z, a.w, b.x, b.y, b.z, b.w};
#pragma unroll
    for (int k = 0; k < 8; ++k) {
      const float tt = __fsub_rn(q[k], f[k]);   // sg(xq - r)
      const float xr = __fadd_rn(f[k], tt);     // x_res (STE)
      f[k] = __fsub_rn(f[k], xr);               // next residual
    }
  }
  if (w == 0) {
#pragma unroll
    for (int k = 0; k < 8; ++k) rs[lane * 8 + k] = f[k];
  }
  __syncthreads();
  const float Rn = np_pairwise_sq512(rs, lane);

  const float* cbs = cb + (size_t)stage * NCODES * DIM;
  const float* Cns = Cn + stage * NCODES;
  float dbest = 3.4e38f;
  int   ibest = 0x7fffffff;
  const int cbeg = w * (NCODES / 4);
  for (int cc = cbeg; cc < cbeg + NCODES / 4; cc += RESCUE_UNROLL) {
    float4 a[RESCUE_UNROLL], b[RESCUE_UNROLL];
#pragma unroll
    for (int u = 0; u < RESCUE_UNROLL; ++u) {
      const float* cp = cbs + (size_t)(cc + u) * DIM + lane * 8;
      a[u] = *(const float4*)cp;
      b[u] = *(const float4*)(cp + 4);
    }
    double s[RESCUE_UNROLL];
#pragma unroll
    for (int u = 0; u < RESCUE_UNROLL; ++u) {
      s[u] = (double)f[0] * a[u].x + (double)f[1] * a[u].y + (double)f[2] * a[u].z + (double)f[3] * a[u].w
           + (double)f[4] * b[u].x + (double)f[5] * b[u].y + (double)f[6] * b[u].z + (double)f[7] * b[u].w;
    }
#pragma unroll
    for (int off = 32; off; off >>= 1) {
#pragma unroll
      for (int u = 0; u < RESCUE_UNROLL; ++u) s[u] += __shfl_xor(s[u], off);
    }
#pragma unroll
    for (int u = 0; u < RESCUE_UNROLL; ++u) {
      const float G = (float)s[u];
      const float d = __fsub_rn(__fadd_rn(Rn, Cns[cc + u]), __fmul_rn(2.0f, G));
      if (d < dbest || (d == dbest && (cc + u) < ibest)) { dbest = d; ibest = cc + u; }
    }
  }
  if (lane == 0) { sd[w] = dbest; si[w] = ibest; }
  __syncthreads();
  if (t == 0) {
    float db = sd[0]; int ib = si[0];
#pragma unroll
    for (int ww = 1; ww < 4; ++ww) {
      if (sd[ww] < db || (sd[ww] == db && si[ww] < ib)) { db = sd[ww]; ib = si[ww]; }
    }
    idxf[(size_t)row * NQ + stage] = (float)ib;
  }
}

// ---------------- gather chosen code, accumulate x_q, accumulate loss ----------------
__global__ __launch_bounds__(128)
void update_kernel(const float* __restrict__ x, float* __restrict__ xq_acc,
                   const float* __restrict__ cb, const float* __restrict__ idxf,
                   double* __restrict__ loss_arr, int stage)
{
  const int n = blockIdx.x;
  const int t = threadIdx.x;
  const int idx = (int)idxf[(size_t)n * NQ + stage];
  const size_t g = (size_t)n * DIM + t * 4;

  float4 cv = *(const float4*)(cb + (size_t)idx * DIM + t * 4);
  float4 av;
  if (stage) av = *(const float4*)(xq_acc + g);
  else { av.x = 0.f; av.y = 0.f; av.z = 0.f; av.w = 0.f; }
  av.x += cv.x; av.y += cv.y; av.z += cv.z; av.w += cv.w;
  *(float4*)(xq_acc + g) = av;

  float4 xv = *(const float4*)(x + g);
  const float rx = xv.x - av.x, ry = xv.y - av.y, rz = xv.z - av.z, rw = xv.w - av.w;
  float s = rx * rx + ry * ry + rz * rz + rw * rw;
#pragma unroll
  for (int off = 32; off; off >>= 1) s += __shfl_down(s, off);
  __shared__ float wsum[2];
  if ((t & 63) == 0) wsum[t >> 6] = s;
  __syncthreads();
  if (t == 0) atomicAdd(&loss_arr[n & 511], (double)(wsum[0] + wsum[1]));  // 512-way fan-out
}

__global__ __launch_bounds__(64)
void finalize_kernel(const double* __restrict__ loss_arr, float* __restrict__ out_loss) {
  double s = 0.0;
  for (int i = threadIdx.x; i < 512; i += 64) s += loss_arr[i];
#pragma unroll
  for (int off = 32; off; off >>= 1) s += __shfl_down(s, off);
  if (threadIdx.x == 0)
    *out_loss = (float)(((1.0 + BETA) / ((double)NQ * (double)N_ROWS * (double)DIM)) * s);
}

extern "C" void kernel_launch(void* const* d_in, const int* in_sizes, int n_in,
                              void* d_out, int out_size, void* d_ws, size_t ws_size,
                              hipStream_t stream) {
  const float* x  = (const float*)d_in[0];
  const float* cb = (const float*)d_in[1];

  float* out_xq   = (float*)d_out;                       // [N, D]
  float* out_loss = out_xq + (size_t)N_ROWS * DIM;       // scalar
  float* out_idx  = out_loss + 1;                        // [N, Q] as float

  char* ws = (char*)d_ws;
  double* loss_arr = (double*)(ws + WS_LOSS);
  float*  Cn       = (float*) (ws + WS_CN);
  float*  gap      = (float*) (ws + WS_GAP);
  float4* partials = (float4*)(ws + WS_PART);
  ushort* cb_hi    = (ushort*)(ws + WS_CBH);
  ushort* cb_lo    = (ushort*)(ws + WS_CBL);

  hipMemsetAsync(ws + WS_LOSS, 0, 4096, stream);
  cbsplit_kernel<<<(NQ * NCODES * DIM) / 2048, 256, 0, stream>>>(cb, cb_hi, cb_lo);
  cnorm_kernel<<<NQ * NCODES, 64, 0, stream>>>(cb, Cn);

  for (int q = 0; q < NQ; ++q) {
    const float* cbq = cb + (size_t)q * NCODES * DIM;
    argmax_kernel<<<512 * 16, 256, 0, stream>>>(x, out_xq,
                                                cb_hi + (size_t)q * NCODES * DIM,
                                                cb_lo + (size_t)q * NCODES * DIM,
                                                Cn + q * NCODES, partials, q);
    mergetop_kernel<<<N_ROWS / 256, 256, 0, stream>>>(partials, out_idx, gap, q);
    rescue_kernel<<<N_ROWS, 256, 0, stream>>>(x, cb, Cn, out_idx, gap, q);
    update_kernel<<<N_ROWS, 128, 0, stream>>>(x, out_xq, cbq, out_idx, loss_arr, q);
  }
  finalize_kernel<<<1, 64, 0, stream>>>(loss_arr, out_loss);
}

// Round 2
// 3042.408 us; speedup vs baseline: 2.8441x; 1.6615x over previous
//
#include <hip/hip_runtime.h>
#include <stdint.h>

#define N_ROWS 32768
#define DIM    512
#define NQ     4
#define NCODES 2048
#define BETA   0.25
#define EPS_RESCUE 0.02f   // MFMA-score gap below which we np-mimic rescore ALL codes

typedef __attribute__((ext_vector_type(8))) short bf16x8;
typedef __attribute__((ext_vector_type(4))) float f32x4;

// ---- ws layout (bytes) ----
#define WS_LOSS   0          // 512 doubles (4 KB)
#define WS_CN     4096       // Q*K floats (32 KB)
#define WS_GAP    36864      // N floats (128 KB)
#define WS_PART   167936     // 16 * N float4 (8 MB)
#define WS_CBH    8556544    // Q*K*D ushort (8 MB)
#define WS_CBL    16945152   // Q*K*D ushort (8 MB)
#define WS_RESH   25333760   // N*D ushort (32 MB) residual hi
#define WS_RESL   58888192   // N*D ushort (32 MB) residual lo

__device__ __forceinline__ ushort f2bf(float f) {
  union { float f; uint32_t u; } v; v.f = f;
  uint32_t r = v.u + 0x7fffu + ((v.u >> 16) & 1u);
  return (ushort)(r >> 16);
}
__device__ __forceinline__ float bf2f(ushort h) {
  union { uint32_t u; float f; } v; v.u = ((uint32_t)h) << 16; return v.f;
}

// ---- numpy pairwise sum (blocksize 128, 8-way unrolled) of squares of 512 floats ----
__device__ __forceinline__ float np_pairwise_sq512(const float* buf, int lane) {
  const int blk = lane >> 3, j = lane & 7;
  const float* p = buf + ((lane < 32) ? (blk * 128 + j) : 0);
  float a = p[0];
  float acc = __fmul_rn(a, a);
#pragma unroll
  for (int i = 1; i < 16; ++i) {
    a = p[i * 8];
    acc = __fadd_rn(acc, __fmul_rn(a, a));
  }
  float s[4];
#pragma unroll
  for (int b = 0; b < 4; ++b) {
    const float p0 = __shfl(acc, b * 8 + 0), p1 = __shfl(acc, b * 8 + 1);
    const float p2 = __shfl(acc, b * 8 + 2), p3 = __shfl(acc, b * 8 + 3);
    const float p4 = __shfl(acc, b * 8 + 4), p5 = __shfl(acc, b * 8 + 5);
    const float p6 = __shfl(acc, b * 8 + 6), p7 = __shfl(acc, b * 8 + 7);
    s[b] = __fadd_rn(__fadd_rn(__fadd_rn(p0, p1), __fadd_rn(p2, p3)),
                     __fadd_rn(__fadd_rn(p4, p5), __fadd_rn(p6, p7)));
  }
  return __fadd_rn(__fadd_rn(s[0], s[1]), __fadd_rn(s[2], s[3]));
}

__global__ __launch_bounds__(64)
void cnorm_kernel(const float* __restrict__ cb, float* __restrict__ Cn) {
  const int row = blockIdx.x, lane = threadIdx.x;
  __shared__ float buf[DIM];
  const float* p = cb + (size_t)row * DIM + lane * 8;
  float4 a = *(const float4*)p, b = *(const float4*)(p + 4);
  *(float4*)&buf[lane * 8]     = a;
  *(float4*)&buf[lane * 8 + 4] = b;
  __syncthreads();
  const float v = np_pairwise_sq512(buf, lane);
  if (lane == 0) Cn[row] = v;
}

// ---- split fp32 array into bf16 hi/lo (used for codebooks AND for x at stage 0) ----
__global__ __launch_bounds__(256)
void cbsplit_kernel(const float* __restrict__ cb, ushort* __restrict__ hi, ushort* __restrict__ lo) {
  const size_t i = ((size_t)blockIdx.x * 256 + threadIdx.x) * 8;
  float4 a = *(const float4*)(cb + i), b = *(const float4*)(cb + i + 4);
  const float f[8] = {a.x, a.y, a.z, a.w, b.x, b.y, b.z, b.w};
  ushort h[8], l[8];
#pragma unroll
  for (int j = 0; j < 8; ++j) {
    h[j] = f2bf(f[j]);
    l[j] = f2bf(f[j] - bf2f(h[j]));
  }
  *(ushort4*)(hi + i)     = make_ushort4(h[0], h[1], h[2], h[3]);
  *(ushort4*)(hi + i + 4) = make_ushort4(h[4], h[5], h[6], h[7]);
  *(ushort4*)(lo + i)     = make_ushort4(l[0], l[1], l[2], l[3]);
  *(ushort4*)(lo + i + 4) = make_ushort4(l[4], l[5], l[6], l[7]);
}

__device__ __forceinline__ void top2_insert(float s, int c, float& v1, int& i1, float& v2, int& i2) {
  if (s > v1 || (s == v1 && c < i1)) { v2 = v1; i2 = i1; v1 = s; i1 = c; }
  else if (s > v2 || (s == v2 && c < i2)) { v2 = s; i2 = c; }
}

// ---------------- MFMA bf16x3 score + per-(rowtile,codetile) top-2 ----------------
// v3: swapped operands mfma(code_frag, row_frag) -> D[code][row]: codes live on
// (lq*4+r) per lane, rows on lane&15 -> cheap top-2 (in-lane + 2 shfl rounds).
// A (residual) comes precomputed in bf16 hi/lo -> global_load_lds direct, no VALU split.
// LDS XOR-swizzle: staging fetches kseg (s&3)^((s>>3)&3) into linear dest; reads use
// chunk lq^((lm>>1)&3) -> conflict-free ds_read_b128.
__global__ __launch_bounds__(256, 2)
void argmax_kernel(const ushort* __restrict__ resh, const ushort* __restrict__ resl,
                   const ushort* __restrict__ cbh, const ushort* __restrict__ cbl,
                   const float* __restrict__ Cn, float4* __restrict__ partials)
{
  __shared__ ushort Ah[64 * 32], Al[64 * 32], Bh[128 * 32], Bl[128 * 32];
  __shared__ float4 mbuf[4][64];

  const int t    = threadIdx.x;
  const int lane = t & 63, w = t >> 6;
  const int rt = blockIdx.x & 511, ct = blockIdx.x >> 9;
  const int m0 = rt * 64, c0 = ct * 128;
  const int lm = lane & 15, lq = lane >> 4;

  // staging: lane-sequence s -> LDS row s>>2, chunk s&3 (linear dest); source kseg pre-swizzled
  const int arow  = t >> 2;
  const int bseg8 = (((t & 3) ^ ((t >> 3) & 3)) << 3);   // element offset of 16B chunk
  // read-side swizzle: chunk' = lq ^ ((lm>>1)&3)
  const int fcol = ((lq ^ ((lm >> 1) & 3)) << 3);

  f32x4 acc[2][4];   // [nt codes][mt rows]
#pragma unroll
  for (int nt = 0; nt < 2; ++nt)
#pragma unroll
    for (int mt = 0; mt < 4; ++mt) acc[nt][mt] = (f32x4){0.f, 0.f, 0.f, 0.f};

  for (int kc = 0; kc < 16; ++kc) {
    const int k0 = kc * 32;
    __syncthreads();
    // ---- B (codes): async global->LDS, pre-swizzled source ----
#pragma unroll
    for (int i = 0; i < 2; ++i) {
      const int s = i * 256 + t;
      const size_t g = (size_t)(c0 + i * 64 + arow) * DIM + k0 + bseg8;
      __builtin_amdgcn_global_load_lds((__attribute__((address_space(1))) void*)(cbh + g),
                                       (__attribute__((address_space(3))) void*)&Bh[s * 8], 16, 0, 0);
      __builtin_amdgcn_global_load_lds((__attribute__((address_space(1))) void*)(cbl + g),
                                       (__attribute__((address_space(3))) void*)&Bl[s * 8], 16, 0, 0);
    }
    // ---- A (residual): async global->LDS from precomputed bf16 hi/lo ----
    {
      const size_t g = (size_t)(m0 + arow) * DIM + k0 + bseg8;
      __builtin_amdgcn_global_load_lds((__attribute__((address_space(1))) void*)(resh + g),
                                       (__attribute__((address_space(3))) void*)&Ah[t * 8], 16, 0, 0);
      __builtin_amdgcn_global_load_lds((__attribute__((address_space(1))) void*)(resl + g),
                                       (__attribute__((address_space(3))) void*)&Al[t * 8], 16, 0, 0);
    }
    __syncthreads();   // drains vmcnt (global_load_lds)
    // ---- fragments (swizzled read; same row-major B^T pattern for both operands) ----
    bf16x8 rh[4], rl[4], ch[2], cl[2];
#pragma unroll
    for (int mt = 0; mt < 4; ++mt) {
      const int o = (mt * 16 + lm) * 32 + fcol;
      rh[mt] = *(bf16x8*)&Ah[o];
      rl[mt] = *(bf16x8*)&Al[o];
    }
#pragma unroll
    for (int nt = 0; nt < 2; ++nt) {
      const int o = (w * 32 + nt * 16 + lm) * 32 + fcol;
      ch[nt] = *(bf16x8*)&Bh[o];
      cl[nt] = *(bf16x8*)&Bl[o];
    }
    // swapped operands: D[code][row]; term order ch*rh, cl*rh, ch*rl matches the
    // validated (rh*ch, rh*cl, rl*ch) accumulation -> bit-identical scores
#pragma unroll
    for (int nt = 0; nt < 2; ++nt)
#pragma unroll
      for (int mt = 0; mt < 4; ++mt) {
        acc[nt][mt] = __builtin_amdgcn_mfma_f32_16x16x32_bf16(ch[nt], rh[mt], acc[nt][mt], 0, 0, 0);
        acc[nt][mt] = __builtin_amdgcn_mfma_f32_16x16x32_bf16(cl[nt], rh[mt], acc[nt][mt], 0, 0, 0);
        acc[nt][mt] = __builtin_amdgcn_mfma_f32_16x16x32_bf16(ch[nt], rl[mt], acc[nt][mt], 0, 0, 0);
      }
  }
  // ---- epilogue: score = G - 0.5*||c||^2; codes are in-lane (nt,r) + across lq ----
  float hc[2][4];
#pragma unroll
  for (int nt = 0; nt < 2; ++nt)
#pragma unroll
    for (int r = 0; r < 4; ++r)
      hc[nt][r] = 0.5f * Cn[c0 + w * 32 + nt * 16 + lq * 4 + r];

#pragma unroll
  for (int mt = 0; mt < 4; ++mt) {   // row m = mt*16 + lm
    float v1 = -3.4e38f, v2 = -3.4e38f;
    int   i1 = 0x7fffffff, i2 = 0x7fffffff;
#pragma unroll
    for (int nt = 0; nt < 2; ++nt)
#pragma unroll
      for (int r = 0; r < 4; ++r)
        top2_insert(acc[nt][mt][r] - hc[nt][r], c0 + w * 32 + nt * 16 + lq * 4 + r, v1, i1, v2, i2);
#pragma unroll
    for (int off = 16; off <= 32; off <<= 1) {   // merge lanes lm, lm+16, lm+32, lm+48
      const float ov1 = __shfl_xor(v1, off); const int oi1 = __shfl_xor(i1, off);
      const float ov2 = __shfl_xor(v2, off); const int oi2 = __shfl_xor(i2, off);
      top2_insert(ov1, oi1, v1, i1, v2, i2);
      top2_insert(ov2, oi2, v1, i1, v2, i2);
    }
    if (lq == 0) mbuf[w][mt * 16 + lm] = make_float4(v1, (float)i1, v2, (float)i2);
  }
  __syncthreads();
  if (t < 64) {   // merge the 4 waves' top-2 for row t
    float v1 = -3.4e38f, v2 = -3.4e38f;
    int   i1 = 0x7fffffff, i2 = 0x7fffffff;
#pragma unroll
    for (int ww = 0; ww < 4; ++ww) {
      float4 p = mbuf[ww][t];
      top2_insert(p.x, (int)p.y, v1, i1, v2, i2);
      top2_insert(p.z, (int)p.w, v1, i1, v2, i2);
    }
    partials[(size_t)ct * N_ROWS + m0 + t] = make_float4(v1, (float)i1, v2, (float)i2);
  }
}

// ---- merge 16 code-tile partials per row -> idx + gap ----
__global__ __launch_bounds__(256)
void mergetop_kernel(const float4* __restrict__ partials, float* __restrict__ idx_out,
                     float* __restrict__ gap, int stage)
{
  const int row = blockIdx.x * 256 + threadIdx.x;
  float v1 = -3.4e38f, v2 = -3.4e38f;
  int   i1 = 0x7fffffff, i2 = 0x7fffffff;
#pragma unroll
  for (int ctt = 0; ctt < 16; ++ctt) {
    float4 p = partials[(size_t)ctt * N_ROWS + row];
    top2_insert(p.x, (int)p.y, v1, i1, v2, i2);
    top2_insert(p.z, (int)p.w, v1, i1, v2, i2);
  }
  idx_out[(size_t)row * NQ + stage] = (float)i1;
  gap[row] = v1 - v2;
}

// ---------------- np-fp32-mimic rescue (validated) ----------------
#define RESCUE_UNROLL 4

__global__ __launch_bounds__(256)
void rescue_kernel(const float* __restrict__ x, const float* __restrict__ cb,
                   const float* __restrict__ Cn, float* __restrict__ idxf,
                   const float* __restrict__ gap, int stage)
{
  const int row = blockIdx.x;
  if (gap[row] >= EPS_RESCUE) return;
  const int t = threadIdx.x;
  const int lane = t & 63, w = t >> 6;
  __shared__ float rs[DIM];
  __shared__ float sd[4];
  __shared__ int   si[4];

  // every wave computes the identical residual f[8] (deterministic replay)
  float f[8];
  {
    const float* xp = x + (size_t)row * DIM + lane * 8;
    float4 a = *(const float4*)xp, b = *(const float4*)(xp + 4);
    f[0]=a.x; f[1]=a.y; f[2]=a.z; f[3]=a.w; f[4]=b.x; f[5]=b.y; f[6]=b.z; f[7]=b.w;
  }
  for (int p = 0; p < stage; ++p) {
    const int ip = (int)idxf[(size_t)row * NQ + p];
    const float* cp = cb + ((size_t)p * NCODES + ip) * DIM + lane * 8;
    float4 a = *(const float4*)cp, b = *(const float4*)(cp + 4);
    const float q[8] = {a.x, a.y, a.z, a.w, b.x, b.y, b.z, b.w};
#pragma unroll
    for (int k = 0; k < 8; ++k) {
      const float tt = __fsub_rn(q[k], f[k]);   // sg(xq - r)
      const float xr = __fadd_rn(f[k], tt);     // x_res (STE)
      f[k] = __fsub_rn(f[k], xr);               // next residual
    }
  }
  if (w == 0) {
#pragma unroll
    for (int k = 0; k < 8; ++k) rs[lane * 8 + k] = f[k];
  }
  __syncthreads();
  const float Rn = np_pairwise_sq512(rs, lane);

  const float* cbs = cb + (size_t)stage * NCODES * DIM;
  const float* Cns = Cn + stage * NCODES;
  float dbest = 3.4e38f;
  int   ibest = 0x7fffffff;
  const int cbeg = w * (NCODES / 4);
  for (int cc = cbeg; cc < cbeg + NCODES / 4; cc += RESCUE_UNROLL) {
    float4 a[RESCUE_UNROLL], b[RESCUE_UNROLL];
#pragma unroll
    for (int u = 0; u < RESCUE_UNROLL; ++u) {
      const float* cp = cbs + (size_t)(cc + u) * DIM + lane * 8;
      a[u] = *(const float4*)cp;
      b[u] = *(const float4*)(cp + 4);
    }
    double s[RESCUE_UNROLL];
#pragma unroll
    for (int u = 0; u < RESCUE_UNROLL; ++u) {
      s[u] = (double)f[0] * a[u].x + (double)f[1] * a[u].y + (double)f[2] * a[u].z + (double)f[3] * a[u].w
           + (double)f[4] * b[u].x + (double)f[5] * b[u].y + (double)f[6] * b[u].z + (double)f[7] * b[u].w;
    }
#pragma unroll
    for (int off = 32; off; off >>= 1) {
#pragma unroll
      for (int u = 0; u < RESCUE_UNROLL; ++u) s[u] += __shfl_xor(s[u], off);
    }
#pragma unroll
    for (int u = 0; u < RESCUE_UNROLL; ++u) {
      const float G = (float)s[u];
      const float d = __fsub_rn(__fadd_rn(Rn, Cns[cc + u]), __fmul_rn(2.0f, G));
      if (d < dbest || (d == dbest && (cc + u) < ibest)) { dbest = d; ibest = cc + u; }
    }
  }
  if (lane == 0) { sd[w] = dbest; si[w] = ibest; }
  __syncthreads();
  if (t == 0) {
    float db = sd[0]; int ib = si[0];
#pragma unroll
    for (int ww = 1; ww < 4; ++ww) {
      if (sd[ww] < db || (sd[ww] == db && si[ww] < ib)) { db = sd[ww]; ib = si[ww]; }
    }
    idxf[(size_t)row * NQ + stage] = (float)ib;
  }
}

// ---------------- gather chosen code, accumulate x_q, loss, next-stage residual ----------------
__global__ __launch_bounds__(128)
void update_kernel(const float* __restrict__ x, float* __restrict__ xq_acc,
                   const float* __restrict__ cb, const float* __restrict__ idxf,
                   double* __restrict__ loss_arr,
                   ushort* __restrict__ resh, ushort* __restrict__ resl, int stage)
{
  const int n = blockIdx.x;
  const int t = threadIdx.x;
  const int idx = (int)idxf[(size_t)n * NQ + stage];
  const size_t g = (size_t)n * DIM + t * 4;

  float4 cv = *(const float4*)(cb + (size_t)idx * DIM + t * 4);
  float4 av;
  if (stage) av = *(const float4*)(xq_acc + g);
  else { av.x = 0.f; av.y = 0.f; av.z = 0.f; av.w = 0.f; }
  av.x += cv.x; av.y += cv.y; av.z += cv.z; av.w += cv.w;
  *(float4*)(xq_acc + g) = av;

  float4 xv = *(const float4*)(x + g);
  const float rx = xv.x - av.x, ry = xv.y - av.y, rz = xv.z - av.z, rw = xv.w - av.w;

  // next-stage residual bf16 hi/lo split (identical formula to cbsplit on x - xq_acc)
  {
    ushort4 h, l;
    h.x = f2bf(rx); l.x = f2bf(rx - bf2f(h.x));
    h.y = f2bf(ry); l.y = f2bf(ry - bf2f(h.y));
    h.z = f2bf(rz); l.z = f2bf(rz - bf2f(h.z));
    h.w = f2bf(rw); l.w = f2bf(rw - bf2f(h.w));
    *(ushort4*)(resh + g) = h;
    *(ushort4*)(resl + g) = l;
  }

  float s = rx * rx + ry * ry + rz * rz + rw * rw;
#pragma unroll
  for (int off = 32; off; off >>= 1) s += __shfl_down(s, off);
  __shared__ float wsum[2];
  if ((t & 63) == 0) wsum[t >> 6] = s;
  __syncthreads();
  if (t == 0) atomicAdd(&loss_arr[n & 511], (double)(wsum[0] + wsum[1]));  // 512-way fan-out
}

__global__ __launch_bounds__(64)
void finalize_kernel(const double* __restrict__ loss_arr, float* __restrict__ out_loss) {
  double s = 0.0;
  for (int i = threadIdx.x; i < 512; i += 64) s += loss_arr[i];
#pragma unroll
  for (int off = 32; off; off >>= 1) s += __shfl_down(s, off);
  if (threadIdx.x == 0)
    *out_loss = (float)(((1.0 + BETA) / ((double)NQ * (double)N_ROWS * (double)DIM)) * s);
}

extern "C" void kernel_launch(void* const* d_in, const int* in_sizes, int n_in,
                              void* d_out, int out_size, void* d_ws, size_t ws_size,
                              hipStream_t stream) {
  const float* x  = (const float*)d_in[0];
  const float* cb = (const float*)d_in[1];

  float* out_xq   = (float*)d_out;                       // [N, D]
  float* out_loss = out_xq + (size_t)N_ROWS * DIM;       // scalar
  float* out_idx  = out_loss + 1;                        // [N, Q] as float

  char* ws = (char*)d_ws;
  double* loss_arr = (double*)(ws + WS_LOSS);
  float*  Cn       = (float*) (ws + WS_CN);
  float*  gap      = (float*) (ws + WS_GAP);
  float4* partials = (float4*)(ws + WS_PART);
  ushort* cb_hi    = (ushort*)(ws + WS_CBH);
  ushort* cb_lo    = (ushort*)(ws + WS_CBL);
  ushort* res_hi   = (ushort*)(ws + WS_RESH);
  ushort* res_lo   = (ushort*)(ws + WS_RESL);

  hipMemsetAsync(ws + WS_LOSS, 0, 4096, stream);
  cbsplit_kernel<<<(NQ * NCODES * DIM) / 2048, 256, 0, stream>>>(cb, cb_hi, cb_lo);
  cbsplit_kernel<<<((size_t)N_ROWS * DIM) / 2048, 256, 0, stream>>>(x, res_hi, res_lo);  // stage-0 residual = x
  cnorm_kernel<<<NQ * NCODES, 64, 0, stream>>>(cb, Cn);

  for (int q = 0; q < NQ; ++q) {
    const float* cbq = cb + (size_t)q * NCODES * DIM;
    argmax_kernel<<<512 * 16, 256, 0, stream>>>(res_hi, res_lo,
                                                cb_hi + (size_t)q * NCODES * DIM,
                                                cb_lo + (size_t)q * NCODES * DIM,
                                                Cn + q * NCODES, partials);
    mergetop_kernel<<<N_ROWS / 256, 256, 0, stream>>>(partials, out_idx, gap, q);
    rescue_kernel<<<N_ROWS, 256, 0, stream>>>(x, cb, Cn, out_idx, gap, q);
    update_kernel<<<N_ROWS, 128, 0, stream>>>(x, out_xq, cbq, out_idx, loss_arr, res_hi, res_lo, q);
  }
  finalize_kernel<<<1, 64, 0, stream>>>(loss_arr, out_loss);
}